// Round 15
// baseline (389.869 us; speedup 1.0000x reference)
//
#include <hip/hip_runtime.h>
#include <hip/hip_bf16.h>
#include <stdint.h>

using bf16 = __hip_bfloat16;
typedef __bf16 bf16x8 __attribute__((ext_vector_type(8)));
typedef float f32x4 __attribute__((ext_vector_type(4)));

__device__ __forceinline__ void gload_lds16(const bf16* g, bf16* l) {
  __builtin_amdgcn_global_load_lds(
      (const __attribute__((address_space(1))) void*)g,
      (__attribute__((address_space(3))) void*)l, 16, 0, 0);
}

#define BARRIER() asm volatile("s_barrier" ::: "memory")

// ---------------- merged f32 -> bf16 conversion (5 small segments) ---------
struct CvtArgs {
  const float* src[5];
  bf16* dst[5];
  int n[5];
  int bstart[6];
};

__global__ __launch_bounds__(256) void cvt_all(CvtArgs a) {
  int seg = 0;
#pragma unroll
  for (int i = 0; i < 4; ++i)
    if ((int)blockIdx.x >= a.bstart[i + 1]) seg = i + 1;
  const int nb = a.bstart[seg + 1] - a.bstart[seg];
  const int lb = blockIdx.x - a.bstart[seg];
  const float* __restrict__ in = a.src[seg];
  bf16* __restrict__ out = a.dst[seg];
  const int n = a.n[seg];
  const int stride = nb * 256 * 4;
  for (int i = (lb * 256 + (int)threadIdx.x) * 4; i < n; i += stride) {
    float4 v = *reinterpret_cast<const float4*>(in + i);
    union { bf16 h[4]; uint2 u; } o;
    o.h[0] = __float2bfloat16(v.x);
    o.h[1] = __float2bfloat16(v.y);
    o.h[2] = __float2bfloat16(v.z);
    o.h[3] = __float2bfloat16(v.w);
    *reinterpret_cast<uint2*>(out + i) = o.u;
  }
}

// --- 128x128 bf16 GEMM: BK=64, 2-phase prefetch, XOR-swizzled LDS ---------
template <int EPI>
__global__ __launch_bounds__(256)
void gemm128(const bf16* __restrict__ A0, const bf16* __restrict__ A1,
             int aSplit, int ldA0, int ldA1,
             const bf16* __restrict__ B0, const bf16* __restrict__ B1,
             int bSplit, int ldB0, int ldB1,
             int MB, int N, int K,
             const float* __restrict__ bias,
             const float* __restrict__ hidden,
             const bf16* __restrict__ zbuf,
             bf16* __restrict__ obf_a,
             bf16* __restrict__ obf_b,
             float* __restrict__ of32,
             int gemmBlocks,
             const float* __restrict__ csrc,
             bf16* __restrict__ cdst, int cn) {
  const int tid = threadIdx.x;
  if ((int)blockIdx.x >= gemmBlocks) {  // ---- converter path ----
    const int cb = blockIdx.x - gemmBlocks;
    const int ncb = gridDim.x - gemmBlocks;
    const int stride = ncb * 256 * 4;
    for (int i = (cb * 256 + tid) * 4; i < cn; i += stride) {
      float4 v = *reinterpret_cast<const float4*>(csrc + i);
      union { bf16 h[4]; uint2 u; } o;
      o.h[0] = __float2bfloat16(v.x);
      o.h[1] = __float2bfloat16(v.y);
      o.h[2] = __float2bfloat16(v.z);
      o.h[3] = __float2bfloat16(v.w);
      *reinterpret_cast<uint2*>(cdst + i) = o.u;
    }
    return;
  }
  __shared__ bf16 lA[2][128 * 64];
  __shared__ bf16 lB[2][128 * 64];
  const int wave = tid >> 6;
  const int lane = tid & 63;
  const int cpx = gemmBlocks >> 3;
  const int swz = ((int)blockIdx.x & 7) * cpx + ((int)blockIdx.x >> 3);
  const int bm = swz % MB;
  const int bn = swz / MB;
  const int wr = wave >> 1, wc = wave & 1;   // 2x2 wave grid, 64x64 each
  const int l8 = lane >> 3;
  const int gcol = ((lane & 7) ^ l8) * 8;    // pre-swizzled global k offset
  const int lrow = lane & 15;
  const int kb0 = (lane >> 4) * 16;          // byte offset within 64B half
  const int xm = (lane & 7) << 4;            // read-side XOR = (row&7)*16
  const int nkt = K >> 6;

  auto STAGEK = [&](int buf, int kt) {
    if (kt >= nkt) return;
    const int kb = kt << 6;
    const bf16* Ap; int lda, ka;
    if (kb < aSplit) { Ap = A0; lda = ldA0; ka = kb; }
    else             { Ap = A1; lda = ldA1; ka = kb - aSplit; }
    const bf16* Bp; int ldb, kbb;
    if (kb < bSplit) { Bp = B0; ldb = ldB0; kbb = kb; }
    else             { Bp = B1; ldb = ldB1; kbb = kb - bSplit; }
#pragma unroll
    for (int h = 0; h < 2; ++h)
#pragma unroll
      for (int j = 0; j < 2; ++j) {
        const int r0 = h * 64 + wave * 16 + j * 8;
        gload_lds16(Ap + (size_t)(bm * 128 + r0 + l8) * lda + ka + gcol,
                    &lA[buf][r0 * 64]);
        gload_lds16(Bp + (size_t)(bn * 128 + r0 + l8) * ldb + kbb + gcol,
                    &lB[buf][r0 * 64]);
      }
  };
  auto RDA = [&](int buf, int row, int ks) {
    return *reinterpret_cast<const bf16x8*>(
        reinterpret_cast<const char*>(&lA[buf][0]) + row * 128 +
        ((ks * 64 + kb0) ^ xm));
  };
  auto RDB = [&](int buf, int row, int ks) {
    return *reinterpret_cast<const bf16x8*>(
        reinterpret_cast<const char*>(&lB[buf][0]) + row * 128 +
        ((ks * 64 + kb0) ^ xm));
  };

  f32x4 acc[4][4] = {};

  STAGEK(0, 0);
  asm volatile("s_waitcnt vmcnt(0)" ::: "memory");
  BARRIER();

  for (int kt = 0; kt < nkt; ++kt) {
    const int buf = kt & 1;
    STAGEK(buf ^ 1, kt + 1);  // prefetch next tile into the other buffer
    bf16x8 af[4][2], bfr[4][2];
#pragma unroll
    for (int f = 0; f < 4; ++f)
#pragma unroll
      for (int ks = 0; ks < 2; ++ks) {
        af[f][ks] = RDA(buf, wr * 64 + f * 16 + lrow, ks);
        bfr[f][ks] = RDB(buf, wc * 64 + f * 16 + lrow, ks);
      }
    __builtin_amdgcn_s_setprio(1);
#pragma unroll
    for (int fm = 0; fm < 4; ++fm)
#pragma unroll
      for (int fn = 0; fn < 4; ++fn)
#pragma unroll
        for (int ks = 0; ks < 2; ++ks)
          acc[fm][fn] = __builtin_amdgcn_mfma_f32_16x16x32_bf16(
              af[fm][ks], bfr[fn][ks], acc[fm][fn], 0, 0, 0);
    __builtin_amdgcn_s_setprio(0);
    asm volatile("s_waitcnt vmcnt(0)" ::: "memory");  // next tile landed
    BARRIER();  // all waves done reading buf + next tile complete
  }

  const int rb = bm * 128 + wr * 64 + (lane >> 4) * 4;
  const int cb = bn * 128 + wc * 64 + lrow;
#pragma unroll
  for (int fm = 0; fm < 4; ++fm) {
#pragma unroll
    for (int fn = 0; fn < 4; ++fn) {
#pragma unroll
      for (int j = 0; j < 4; ++j) {
        const int m = rb + fm * 16 + j;
        const int n = cb + fn * 16;
        float v = acc[fm][fn][j];
        if (EPI == 1) {
          v = 1.0f / (1.0f + __expf(-(v + bias[n])));
          if (n < 2048) {
            obf_a[(size_t)m * 2048 + n] = __float2bfloat16(v);
          } else {
            const int nn = n - 2048;
            obf_b[(size_t)m * 2048 + nn] =
                __float2bfloat16(v * hidden[(size_t)m * 2048 + nn]);
          }
        } else if (EPI == 2) {
          const float e = __expf(2.0f * (v + bias[n]));
          const float hc = (e - 1.0f) / (e + 1.0f);
          const float z = __bfloat162float(zbuf[(size_t)m * 2048 + n]);
          const float hd = hidden[(size_t)m * 2048 + n];
          const float h = z * hd + (1.0f - z) * hc;
          of32[(size_t)m * 2048 + n] = h;
          obf_a[(size_t)m * 2048 + n] = __float2bfloat16(h);
        }
      }
    }
  }
}

// ------ 256x256 8-phase bf16 GEMM, deep pipeline, 4 barriers/iter ----------
// Stages moved to even phases (ph0:a2, ph2:pl3, ph4:a0, ph6:pl4); barrier
// only after odd phases. Hazards: pl3 last LDS-read @ph0 -> barrier@ph1-end
// precedes ph2 write; pl4 read @ph4 -> barrier@ph5-end precedes ph6 write;
// a0 read ph0-3 -> barrier@ph3-end precedes ph4 write; a2 unread this iter.
// vmcnt(8)@ph3/ph7 unchanged (FIFO: drains {A(t+1),B(t+1)} / {A(t+2),B(t+2)}
// with 5-7 phases slack).
__global__ __launch_bounds__(512, 2)
void gemm256_f(const bf16* __restrict__ A, const bf16* __restrict__ W,
               const float* __restrict__ bias, uint32_t* __restrict__ lgt,
               float2* __restrict__ partials, int MB, int K, int NPB) {
  __shared__ bf16 lds[5][256 * 64];  // 163840 B = full LDS pool
  const int tid = threadIdx.x;
  const int w = tid >> 6, lane = tid & 63;
  const int nwg = gridDim.x;
  const int q8 = nwg >> 3, r8 = nwg & 7;
  const int xcd = (int)blockIdx.x & 7, lid = (int)blockIdx.x >> 3;
  const int swz =
      (xcd < r8 ? xcd * (q8 + 1) : r8 * (q8 + 1) + (xcd - r8) * q8) + lid;
  const int bm = swz % MB, bn = swz / MB;
  const int wr = w >> 2, wc = w & 3;   // 2x4 wave grid
  const int l8 = lane >> 3;
  const int gcol = ((lane & 7) ^ l8) * 8;   // pre-swizzled global k-elem ofs
  const int rA = lane & 15;
  const int kb0 = (lane >> 4) * 16;
  const int xm = (lane & 7) << 4;
  const int nkt = K >> 6, niter = nkt >> 1;
  const bf16* gA = A + (size_t)bm * 256 * K;
  const bf16* gB = W + (size_t)bn * 256 * K;

  auto STAGE2 = [&](int plane, int kt, const bf16* g) {  // full 256x64 tile
    if (kt > nkt - 1) kt = nkt - 1;  // clamp: keep vmcnt counts uniform
#pragma unroll
    for (int h = 0; h < 2; ++h) {
      const int r0 = h * 128 + w * 16;
#pragma unroll
      for (int j = 0; j < 2; ++j)
        gload_lds16(g + (size_t)(r0 + j * 8 + l8) * K + kt * 64 + gcol,
                    &lds[plane][(r0 + j * 8) * 64]);
    }
  };
  auto RD = [&](int plane, int row, int ks) {
    const int off = row * 128 + ((ks * 64 + kb0) ^ xm);
    return *reinterpret_cast<const bf16x8*>(
        reinterpret_cast<const char*>(&lds[plane][0]) + off);
  };

  f32x4 acc[8][4] = {};

  int a0 = 0, a1 = 1, a2 = 2;
  STAGE2(a0, 0, gA); STAGE2(3, 0, gB);
  STAGE2(a1, 1, gA); STAGE2(4, 1, gB);
  asm volatile("s_waitcnt vmcnt(8)" ::: "memory");
  BARRIER();

  for (int it = 0; it < niter; ++it) {
    const int t = it << 1;
    const bool last = (it == niter - 1);
    bf16x8 bfr[4][2];
#pragma unroll
    for (int ph = 0; ph < 8; ++ph) {
      const int buf = ph >> 2, q = ph & 3;
      const int ap = buf ? a1 : a0;
      const int bp = 3 + buf;
      bf16x8 af[2][2];
      if (q == 0) {
#pragma unroll
        for (int n = 0; n < 4; ++n)
#pragma unroll
          for (int ks = 0; ks < 2; ++ks)
            bfr[n][ks] = RD(bp, wc * 64 + n * 16 + rA, ks);
      }
#pragma unroll
      for (int mm = 0; mm < 2; ++mm)
#pragma unroll
        for (int ks = 0; ks < 2; ++ks)
          af[mm][ks] = RD(ap, wr * 128 + (q * 2 + mm) * 16 + rA, ks);

      if (ph == 0)      STAGE2(a2, t + 2, gA);  // a2 unread this iter
      else if (ph == 2) STAGE2(3, t + 2, gB);   // pl3 read @ph0, bar@ph1-end
      else if (ph == 4) STAGE2(a0, t + 3, gA);  // a0 drained @ph3-end bar
      else if (ph == 6) STAGE2(4, t + 3, gB);   // pl4 read @ph4, bar@ph5-end

      __builtin_amdgcn_s_setprio(1);
#pragma unroll
      for (int mm = 0; mm < 2; ++mm)
#pragma unroll
        for (int n = 0; n < 4; ++n)
#pragma unroll
          for (int ks = 0; ks < 2; ++ks)
            acc[q * 2 + mm][n] = __builtin_amdgcn_mfma_f32_16x16x32_bf16(
                af[mm][ks], bfr[n][ks], acc[q * 2 + mm][n], 0, 0, 0);
      __builtin_amdgcn_s_setprio(0);

      if (ph == 3 || ph == 7)
        asm volatile("s_waitcnt vmcnt(8)" ::: "memory");
      if ((ph & 1) && !(ph == 7 && last)) BARRIER();
    }
    // rotate A planes: next iter reads {A(t+2)=a2, A(t+3)=a0}; free = a1
    const int na0 = a2, na1 = a0, na2 = a1;
    a0 = na0; a1 = na1; a2 = na2;
  }
  asm volatile("s_waitcnt vmcnt(0) lgkmcnt(0)" ::: "memory");
  __syncthreads();  // all LDS traffic done; planes now reusable as scratch

  // ---- fused epilogue: bias, row stats, bf16 logits (fragment layout) ----
  float* red = (float*)&lds[0][0];     // [4][256] overlay
  float* red2 = red + 1024;            // [256]
  const int outc = bn * 256 + wc * 64 + rA;
  float bb[4];
#pragma unroll
  for (int n = 0; n < 4; ++n) bb[n] = bias[outc + n * 16];
#pragma unroll
  for (int m = 0; m < 8; ++m)
#pragma unroll
    for (int n = 0; n < 4; ++n)
#pragma unroll
      for (int j = 0; j < 4; ++j) acc[m][n][j] += bb[n];

  const int q4 = lane >> 4;
  const int rowb = wr * 128 + q4 * 4;
#pragma unroll
  for (int m = 0; m < 8; ++m)
#pragma unroll
    for (int j = 0; j < 4; ++j) {
      float x = fmaxf(fmaxf(acc[m][0][j], acc[m][1][j]),
                      fmaxf(acc[m][2][j], acc[m][3][j]));
      x = fmaxf(x, __shfl_xor(x, 1));
      x = fmaxf(x, __shfl_xor(x, 2));
      x = fmaxf(x, __shfl_xor(x, 4));
      x = fmaxf(x, __shfl_xor(x, 8));
      if (rA == 0) red[wc * 256 + rowb + m * 16 + j] = x;
    }
  __syncthreads();
  if (tid < 256)
    red2[tid] = fmaxf(fmaxf(red[0 * 256 + tid], red[1 * 256 + tid]),
                      fmaxf(red[2 * 256 + tid], red[3 * 256 + tid]));
  __syncthreads();

  uint32_t* lgtb = lgt + (size_t)(bm * NPB + bn) * (64 * 512) + tid;
#pragma unroll
  for (int m = 0; m < 8; ++m) {
    const int r0 = rowb + m * 16;
    float s[4];
#pragma unroll
    for (int j = 0; j < 4; ++j) {
      const float fm = red2[r0 + j];
      float e = __expf(acc[m][0][j] - fm) + __expf(acc[m][1][j] - fm) +
                __expf(acc[m][2][j] - fm) + __expf(acc[m][3][j] - fm);
      e += __shfl_xor(e, 1);
      e += __shfl_xor(e, 2);
      e += __shfl_xor(e, 4);
      e += __shfl_xor(e, 8);
      s[j] = e;
    }
#pragma unroll
    for (int j = 0; j < 4; ++j)
      if (rA == 0) red[wc * 256 + r0 + j] = s[j];
#pragma unroll
    for (int n = 0; n < 4; ++n)
#pragma unroll
      for (int k = 0; k < 2; ++k) {
        union { bf16 h[2]; uint32_t u; } pk;
        pk.h[0] = __float2bfloat16(acc[m][n][2 * k]);
        pk.h[1] = __float2bfloat16(acc[m][n][2 * k + 1]);
        lgtb[(size_t)(m * 8 + n * 2 + k) * 512] = pk.u;
      }
  }
  __syncthreads();
  if (tid < 256) {
    const float ssum = red[0 * 256 + tid] + red[1 * 256 + tid] +
                       red[2 * 256 + tid] + red[3 * 256 + tid];
    partials[(size_t)(bm * 256 + tid) * NPB + bn] =
        make_float2(red2[tid], ssum);
  }
}

// ---------------- lse reduce: 1024 rows x NPB partials -> lse[row] ---------
__global__ __launch_bounds__(128) void lse_reduce(
    const float2* __restrict__ partials, float* __restrict__ lse, int NPB) {
  const int row = blockIdx.x;
  const int t = threadIdx.x;
  float m = -3.4e38f, s = 0.0f;
  if (t < NPB) {
    float2 p = partials[(size_t)row * NPB + t];
    m = p.x;
    s = p.y;
  }
#pragma unroll
  for (int o = 32; o; o >>= 1) {
    const float om = __shfl_xor(m, o), os = __shfl_xor(s, o);
    const float nm = fmaxf(m, om);
    s = s * __expf(m - nm) + os * __expf(om - nm);
    m = nm;
  }
  __shared__ float sm[2], ss[2];
  if ((t & 63) == 0) { sm[t >> 6] = m; ss[t >> 6] = s; }
  __syncthreads();
  if (t == 0) {
    const float M = fmaxf(sm[0], sm[1]);
    const float S = ss[0] * __expf(sm[0] - M) + ss[1] * __expf(sm[1] - M);
    lse[row] = M + __logf(S);
  }
}

// --------- final: read fragment-layout bf16 logits, write log_softmax ------
__global__ __launch_bounds__(512) void ls_final(
    const uint32_t* __restrict__ lgt, const float* __restrict__ lse,
    float* __restrict__ out, int NPB) {
  const int blk = blockIdx.x;
  const int bm = blk / NPB, bn = blk % NPB;
  const int t = threadIdx.x;
  const int w = t >> 6, lane = t & 63;
  const int wr = w >> 2, wc = w & 3, q4 = lane >> 4, rAc = lane & 15;
  const uint32_t* src = lgt + (size_t)blk * (64 * 512) + t;
  const int col = bn * 256 + wc * 64 + rAc;
  const int row0 = bm * 256 + wr * 128 + q4 * 4;
#pragma unroll 4
  for (int fp = 0; fp < 64; ++fp) {
    const int m = fp >> 3, n = (fp >> 1) & 3, k = fp & 1;
    const uint32_t u = src[(size_t)fp * 512];
    const int r = row0 + m * 16 + 2 * k;
    const int c = col + n * 16;
    const float lo = __uint_as_float(u << 16);
    const float hi = __uint_as_float(u & 0xffff0000u);
    out[(size_t)r * 32000 + c] = lo - lse[r];
    out[(size_t)(r + 1) * 32000 + c] = hi - lse[r + 1];
  }
}

extern "C" void kernel_launch(void* const* d_in, const int* in_sizes, int n_in,
                              void* d_out, int out_size, void* d_ws,
                              size_t ws_size, hipStream_t stream) {
  const float* input  = (const float*)d_in[0];
  const float* hidden = (const float*)d_in[1];
  const float* W_i2g  = (const float*)d_in[2];
  const float* b_i2g  = (const float*)d_in[3];
  const float* W_x2h  = (const float*)d_in[4];
  const float* b_x2h  = (const float*)d_in[5];
  const float* W_h2h  = (const float*)d_in[6];
  const float* W_h2o  = (const float*)d_in[7];
  const float* b_h2o  = (const float*)d_in[8];

  float* out_ls = (float*)d_out;                 // [1024,32000]
  float* out_h  = out_ls + (size_t)1024 * 32000; // [1024,2048]

  char* ws = (char*)d_ws;
  bf16* inp_bf     = (bf16*)(ws + 0);          //  2 MB
  bf16* hid_bf     = (bf16*)(ws + 2097152);    //  4 MB
  bf16* wi_bf      = (bf16*)(ws + 6291456);    // 24 MB
  bf16* wx_bf      = (bf16*)(ws + 31457280);   //  4 MB
  bf16* wh_bf      = (bf16*)(ws + 35651584);   //  8 MB
  bf16* z_bf       = (bf16*)(ws + 44040192);   //  4 MB
  bf16* rh_bf      = (bf16*)(ws + 48234496);   //  4 MB
  bf16* h_bf       = (bf16*)(ws + 52428800);   //  4 MB
  bf16* wo_bf      = (bf16*)(ws + 56623104);   // 125 MB
  uint32_t* lgt    = (uint32_t*)(ws + 187695104);  // 65.5 MB
  float2* partials = (float2*)(ws + 253231104);    // 1 MB
  float* lse       = (float*)(ws + 254255104);     // 4 KB

  // small tensors only (W_h2o converts inside the gemm128 launches)
  CvtArgs ca;
  ca.src[0] = input;  ca.dst[0] = inp_bf; ca.n[0] = 1024 * 1024;
  ca.src[1] = hidden; ca.dst[1] = hid_bf; ca.n[1] = 1024 * 2048;
  ca.src[2] = W_i2g;  ca.dst[2] = wi_bf;  ca.n[2] = 4096 * 3072;
  ca.src[3] = W_x2h;  ca.dst[3] = wx_bf;  ca.n[3] = 2048 * 1024;
  ca.src[4] = W_h2h;  ca.dst[4] = wh_bf;  ca.n[4] = 2048 * 2048;
  const int bs[6] = {0, 24, 72, 370, 418, 512};
  for (int i = 0; i < 6; ++i) ca.bstart[i] = bs[i];
  cvt_all<<<512, 256, 0, stream>>>(ca);

  const int HALF_WO = 32000 * 2048 / 2;  // 32,768,000 elements

  // gates GEMM (256 blocks) + first half of W_h2o conversion (384 blocks)
  gemm128<1><<<256 + 384, 256, 0, stream>>>(
      inp_bf, hid_bf, 1024, 1024, 2048,
      wi_bf, wi_bf, 1 << 30, 3072, 3072,
      8, 4096, 3072, b_i2g, hidden, nullptr, z_bf, rh_bf, nullptr,
      256, W_h2o, wo_bf, HALF_WO);

  // h_cand GEMM (128 blocks) + second half of W_h2o conversion (512 blocks)
  gemm128<2><<<128 + 512, 256, 0, stream>>>(
      inp_bf, rh_bf, 1024, 1024, 2048,
      wx_bf, wh_bf, 1024, 1024, 2048,
      8, 2048, 3072, b_x2h, hidden, z_bf, h_bf, nullptr, out_h,
      128, W_h2o + HALF_WO, wo_bf + HALF_WO, HALF_WO);

  // logits (bf16 frag layout) + per-block softmax partials
  gemm256_f<<<4 * 125, 512, 0, stream>>>(h_bf, wo_bf, b_h2o, lgt, partials,
                                         4, 2048, 125);

  // lse per row, then final log-softmax write
  lse_reduce<<<1024, 128, 0, stream>>>(partials, lse, 125);
  ls_final<<<500, 512, 0, stream>>>(lgt, lse, out_ls, 125);
}

// Round 16
// 369.371 us; speedup vs baseline: 1.0555x; 1.0555x over previous
//
#include <hip/hip_runtime.h>
#include <hip/hip_bf16.h>
#include <stdint.h>

using bf16 = __hip_bfloat16;
typedef __bf16 bf16x8 __attribute__((ext_vector_type(8)));
typedef float f32x4 __attribute__((ext_vector_type(4)));

__device__ __forceinline__ void gload_lds16(const bf16* g, bf16* l) {
  __builtin_amdgcn_global_load_lds(
      (const __attribute__((address_space(1))) void*)g,
      (__attribute__((address_space(3))) void*)l, 16, 0, 0);
}

#define BARRIER() asm volatile("s_barrier" ::: "memory")

// ---------------- merged f32 -> bf16 conversion (3 segments) ---------------
struct CvtArgs {
  const float* src[3];
  bf16* dst[3];
  int n[3];
  int bstart[4];
};

__global__ __launch_bounds__(256) void cvt_all(CvtArgs a) {
  int seg = 0;
#pragma unroll
  for (int i = 0; i < 2; ++i)
    if ((int)blockIdx.x >= a.bstart[i + 1]) seg = i + 1;
  const int nb = a.bstart[seg + 1] - a.bstart[seg];
  const int lb = blockIdx.x - a.bstart[seg];
  const float* __restrict__ in = a.src[seg];
  bf16* __restrict__ out = a.dst[seg];
  const int n = a.n[seg];
  const int stride = nb * 256 * 4;
  for (int i = (lb * 256 + (int)threadIdx.x) * 4; i < n; i += stride) {
    float4 v = *reinterpret_cast<const float4*>(in + i);
    union { bf16 h[4]; uint2 u; } o;
    o.h[0] = __float2bfloat16(v.x);
    o.h[1] = __float2bfloat16(v.y);
    o.h[2] = __float2bfloat16(v.z);
    o.h[3] = __float2bfloat16(v.w);
    *reinterpret_cast<uint2*>(out + i) = o.u;
  }
}

// --- 128x128 bf16 GEMM: BK=64, 2-phase prefetch, XOR-swizzled LDS ---------
// Converter blocks handle up to 3 (src,dst,n) segments via a virtual
// concatenated index (all n multiples of 4 -> float4 alignment holds).
template <int EPI>
__global__ __launch_bounds__(256)
void gemm128(const bf16* __restrict__ A0, const bf16* __restrict__ A1,
             int aSplit, int ldA0, int ldA1,
             const bf16* __restrict__ B0, const bf16* __restrict__ B1,
             int bSplit, int ldB0, int ldB1,
             int MB, int N, int K,
             const float* __restrict__ bias,
             const float* __restrict__ hidden,
             const bf16* __restrict__ zbuf,
             bf16* __restrict__ obf_a,
             bf16* __restrict__ obf_b,
             float* __restrict__ of32,
             int gemmBlocks,
             const float* __restrict__ csrc0, bf16* __restrict__ cdst0, int cn0,
             const float* __restrict__ csrc1, bf16* __restrict__ cdst1, int cn1,
             const float* __restrict__ csrc2, bf16* __restrict__ cdst2, int cn2) {
  const int tid = threadIdx.x;
  if ((int)blockIdx.x >= gemmBlocks) {  // ---- converter path ----
    const int cb = blockIdx.x - gemmBlocks;
    const int ncb = gridDim.x - gemmBlocks;
    const int stride = ncb * 256 * 4;
    const int tot = cn0 + cn1 + cn2;
    for (int i = (cb * 256 + tid) * 4; i < tot; i += stride) {
      const float* sp; bf16* dp; int off = i;
      if (off < cn0)            { sp = csrc0; dp = cdst0; }
      else if (off < cn0 + cn1) { sp = csrc1; dp = cdst1; off -= cn0; }
      else                      { sp = csrc2; dp = cdst2; off -= cn0 + cn1; }
      float4 v = *reinterpret_cast<const float4*>(sp + off);
      union { bf16 h[4]; uint2 u; } o;
      o.h[0] = __float2bfloat16(v.x);
      o.h[1] = __float2bfloat16(v.y);
      o.h[2] = __float2bfloat16(v.z);
      o.h[3] = __float2bfloat16(v.w);
      *reinterpret_cast<uint2*>(dp + off) = o.u;
    }
    return;
  }
  __shared__ bf16 lA[2][128 * 64];
  __shared__ bf16 lB[2][128 * 64];
  const int wave = tid >> 6;
  const int lane = tid & 63;
  const int cpx = gemmBlocks >> 3;
  const int swz = ((int)blockIdx.x & 7) * cpx + ((int)blockIdx.x >> 3);
  const int bm = swz % MB;
  const int bn = swz / MB;
  const int wr = wave >> 1, wc = wave & 1;   // 2x2 wave grid, 64x64 each
  const int l8 = lane >> 3;
  const int gcol = ((lane & 7) ^ l8) * 8;    // pre-swizzled global k offset
  const int lrow = lane & 15;
  const int kb0 = (lane >> 4) * 16;          // byte offset within 64B half
  const int xm = (lane & 7) << 4;            // read-side XOR = (row&7)*16
  const int nkt = K >> 6;

  auto STAGEK = [&](int buf, int kt) {
    if (kt >= nkt) return;
    const int kb = kt << 6;
    const bf16* Ap; int lda, ka;
    if (kb < aSplit) { Ap = A0; lda = ldA0; ka = kb; }
    else             { Ap = A1; lda = ldA1; ka = kb - aSplit; }
    const bf16* Bp; int ldb, kbb;
    if (kb < bSplit) { Bp = B0; ldb = ldB0; kbb = kb; }
    else             { Bp = B1; ldb = ldB1; kbb = kb - bSplit; }
#pragma unroll
    for (int h = 0; h < 2; ++h)
#pragma unroll
      for (int j = 0; j < 2; ++j) {
        const int r0 = h * 64 + wave * 16 + j * 8;
        gload_lds16(Ap + (size_t)(bm * 128 + r0 + l8) * lda + ka + gcol,
                    &lA[buf][r0 * 64]);
        gload_lds16(Bp + (size_t)(bn * 128 + r0 + l8) * ldb + kbb + gcol,
                    &lB[buf][r0 * 64]);
      }
  };
  auto RDA = [&](int buf, int row, int ks) {
    return *reinterpret_cast<const bf16x8*>(
        reinterpret_cast<const char*>(&lA[buf][0]) + row * 128 +
        ((ks * 64 + kb0) ^ xm));
  };
  auto RDB = [&](int buf, int row, int ks) {
    return *reinterpret_cast<const bf16x8*>(
        reinterpret_cast<const char*>(&lB[buf][0]) + row * 128 +
        ((ks * 64 + kb0) ^ xm));
  };

  f32x4 acc[4][4] = {};

  STAGEK(0, 0);
  asm volatile("s_waitcnt vmcnt(0)" ::: "memory");
  BARRIER();

  for (int kt = 0; kt < nkt; ++kt) {
    const int buf = kt & 1;
    STAGEK(buf ^ 1, kt + 1);  // prefetch next tile into the other buffer
    bf16x8 af[4][2], bfr[4][2];
#pragma unroll
    for (int f = 0; f < 4; ++f)
#pragma unroll
      for (int ks = 0; ks < 2; ++ks) {
        af[f][ks] = RDA(buf, wr * 64 + f * 16 + lrow, ks);
        bfr[f][ks] = RDB(buf, wc * 64 + f * 16 + lrow, ks);
      }
    __builtin_amdgcn_s_setprio(1);
#pragma unroll
    for (int fm = 0; fm < 4; ++fm)
#pragma unroll
      for (int fn = 0; fn < 4; ++fn)
#pragma unroll
        for (int ks = 0; ks < 2; ++ks)
          acc[fm][fn] = __builtin_amdgcn_mfma_f32_16x16x32_bf16(
              af[fm][ks], bfr[fn][ks], acc[fm][fn], 0, 0, 0);
    __builtin_amdgcn_s_setprio(0);
    asm volatile("s_waitcnt vmcnt(0)" ::: "memory");  // next tile landed
    BARRIER();  // all waves done reading buf + next tile complete
  }

  const int rb = bm * 128 + wr * 64 + (lane >> 4) * 4;
  const int cb = bn * 128 + wc * 64 + lrow;
#pragma unroll
  for (int fm = 0; fm < 4; ++fm) {
#pragma unroll
    for (int fn = 0; fn < 4; ++fn) {
#pragma unroll
      for (int j = 0; j < 4; ++j) {
        const int m = rb + fm * 16 + j;
        const int n = cb + fn * 16;
        float v = acc[fm][fn][j];
        if (EPI == 1) {
          v = 1.0f / (1.0f + __expf(-(v + bias[n])));
          if (n < 2048) {
            obf_a[(size_t)m * 2048 + n] = __float2bfloat16(v);
          } else {
            const int nn = n - 2048;
            obf_b[(size_t)m * 2048 + nn] =
                __float2bfloat16(v * hidden[(size_t)m * 2048 + nn]);
          }
        } else if (EPI == 2) {
          const float e = __expf(2.0f * (v + bias[n]));
          const float hc = (e - 1.0f) / (e + 1.0f);
          const float z = __bfloat162float(zbuf[(size_t)m * 2048 + n]);
          const float hd = hidden[(size_t)m * 2048 + n];
          const float h = z * hd + (1.0f - z) * hc;
          of32[(size_t)m * 2048 + n] = h;
          obf_a[(size_t)m * 2048 + n] = __float2bfloat16(h);
        }
      }
    }
  }
}

// ------ 256x256 8-phase bf16 GEMM, deep pipeline, front-loaded staging -----
// (K10 verified schedule: stages @ph0/1/4/5, vmcnt(8) after MFMA @ph3/ph7)
__global__ __launch_bounds__(512, 2)
void gemm256_f(const bf16* __restrict__ A, const bf16* __restrict__ W,
               const float* __restrict__ bias, uint32_t* __restrict__ lgt,
               float2* __restrict__ partials, int MB, int K, int NPB) {
  __shared__ bf16 lds[5][256 * 64];  // 163840 B = full LDS pool
  const int tid = threadIdx.x;
  const int w = tid >> 6, lane = tid & 63;
  const int nwg = gridDim.x;
  const int q8 = nwg >> 3, r8 = nwg & 7;
  const int xcd = (int)blockIdx.x & 7, lid = (int)blockIdx.x >> 3;
  const int swz =
      (xcd < r8 ? xcd * (q8 + 1) : r8 * (q8 + 1) + (xcd - r8) * q8) + lid;
  const int bm = swz % MB, bn = swz / MB;
  const int wr = w >> 2, wc = w & 3;   // 2x4 wave grid
  const int l8 = lane >> 3;
  const int gcol = ((lane & 7) ^ l8) * 8;   // pre-swizzled global k-elem ofs
  const int rA = lane & 15;
  const int kb0 = (lane >> 4) * 16;
  const int xm = (lane & 7) << 4;
  const int nkt = K >> 6, niter = nkt >> 1;
  const bf16* gA = A + (size_t)bm * 256 * K;
  const bf16* gB = W + (size_t)bn * 256 * K;

  auto STAGE2 = [&](int plane, int kt, const bf16* g) {  // full 256x64 tile
    if (kt > nkt - 1) kt = nkt - 1;  // clamp: keep vmcnt counts uniform
#pragma unroll
    for (int h = 0; h < 2; ++h) {
      const int r0 = h * 128 + w * 16;
#pragma unroll
      for (int j = 0; j < 2; ++j)
        gload_lds16(g + (size_t)(r0 + j * 8 + l8) * K + kt * 64 + gcol,
                    &lds[plane][(r0 + j * 8) * 64]);
    }
  };
  auto RD = [&](int plane, int row, int ks) {
    const int off = row * 128 + ((ks * 64 + kb0) ^ xm);
    return *reinterpret_cast<const bf16x8*>(
        reinterpret_cast<const char*>(&lds[plane][0]) + off);
  };

  f32x4 acc[8][4] = {};

  int a0 = 0, a1 = 1, a2 = 2;
  STAGE2(a0, 0, gA); STAGE2(3, 0, gB);
  STAGE2(a1, 1, gA); STAGE2(4, 1, gB);
  asm volatile("s_waitcnt vmcnt(8)" ::: "memory");
  BARRIER();

  for (int it = 0; it < niter; ++it) {
    const int t = it << 1;
    const bool last = (it == niter - 1);
    bf16x8 bfr[4][2];
#pragma unroll
    for (int ph = 0; ph < 8; ++ph) {
      const int buf = ph >> 2, q = ph & 3;
      const int ap = buf ? a1 : a0;
      const int bp = 3 + buf;
      bf16x8 af[2][2];
      if (q == 0) {
#pragma unroll
        for (int n = 0; n < 4; ++n)
#pragma unroll
          for (int ks = 0; ks < 2; ++ks)
            bfr[n][ks] = RD(bp, wc * 64 + n * 16 + rA, ks);
      }
#pragma unroll
      for (int mm = 0; mm < 2; ++mm)
#pragma unroll
        for (int ks = 0; ks < 2; ++ks)
          af[mm][ks] = RD(ap, wr * 128 + (q * 2 + mm) * 16 + rA, ks);

      if (ph == 0)      STAGE2(a2, t + 2, gA);  // a2 unused this iter
      else if (ph == 1) STAGE2(3, t + 2, gB);   // plane3 free after ph0 read
      else if (ph == 4) STAGE2(a0, t + 3, gA);  // a0 freed at ph3 barrier
      else if (ph == 5) STAGE2(4, t + 3, gB);   // plane4 free after ph4 read

      __builtin_amdgcn_s_setprio(1);
#pragma unroll
      for (int mm = 0; mm < 2; ++mm)
#pragma unroll
        for (int n = 0; n < 4; ++n)
#pragma unroll
          for (int ks = 0; ks < 2; ++ks)
            acc[q * 2 + mm][n] = __builtin_amdgcn_mfma_f32_16x16x32_bf16(
                af[mm][ks], bfr[n][ks], acc[q * 2 + mm][n], 0, 0, 0);
      __builtin_amdgcn_s_setprio(0);

      if (ph == 3 || ph == 7)
        asm volatile("s_waitcnt vmcnt(8)" ::: "memory");
      if (!(ph == 7 && last)) BARRIER();
    }
    // rotate A planes: next iter reads {A(t+2)=a2, A(t+3)=a0}; free = a1
    const int na0 = a2, na1 = a0, na2 = a1;
    a0 = na0; a1 = na1; a2 = na2;
  }
  asm volatile("s_waitcnt vmcnt(0) lgkmcnt(0)" ::: "memory");
  __syncthreads();  // all LDS traffic done; planes now reusable as scratch

  // ---- fused epilogue: bias, row stats, bf16 logits (fragment layout) ----
  float* red = (float*)&lds[0][0];     // [4][256] overlay
  float* red2 = red + 1024;            // [256]
  const int outc = bn * 256 + wc * 64 + rA;
  float bb[4];
#pragma unroll
  for (int n = 0; n < 4; ++n) bb[n] = bias[outc + n * 16];
#pragma unroll
  for (int m = 0; m < 8; ++m)
#pragma unroll
    for (int n = 0; n < 4; ++n)
#pragma unroll
      for (int j = 0; j < 4; ++j) acc[m][n][j] += bb[n];

  const int q4 = lane >> 4;
  const int rowb = wr * 128 + q4 * 4;
#pragma unroll
  for (int m = 0; m < 8; ++m)
#pragma unroll
    for (int j = 0; j < 4; ++j) {
      float x = fmaxf(fmaxf(acc[m][0][j], acc[m][1][j]),
                      fmaxf(acc[m][2][j], acc[m][3][j]));
      x = fmaxf(x, __shfl_xor(x, 1));
      x = fmaxf(x, __shfl_xor(x, 2));
      x = fmaxf(x, __shfl_xor(x, 4));
      x = fmaxf(x, __shfl_xor(x, 8));
      if (rA == 0) red[wc * 256 + rowb + m * 16 + j] = x;
    }
  __syncthreads();
  if (tid < 256)
    red2[tid] = fmaxf(fmaxf(red[0 * 256 + tid], red[1 * 256 + tid]),
                      fmaxf(red[2 * 256 + tid], red[3 * 256 + tid]));
  __syncthreads();

  uint32_t* lgtb = lgt + (size_t)(bm * NPB + bn) * (64 * 512) + tid;
#pragma unroll
  for (int m = 0; m < 8; ++m) {
    const int r0 = rowb + m * 16;
    float s[4];
#pragma unroll
    for (int j = 0; j < 4; ++j) {
      const float fm = red2[r0 + j];
      float e = __expf(acc[m][0][j] - fm) + __expf(acc[m][1][j] - fm) +
                __expf(acc[m][2][j] - fm) + __expf(acc[m][3][j] - fm);
      e += __shfl_xor(e, 1);
      e += __shfl_xor(e, 2);
      e += __shfl_xor(e, 4);
      e += __shfl_xor(e, 8);
      s[j] = e;
    }
#pragma unroll
    for (int j = 0; j < 4; ++j)
      if (rA == 0) red[wc * 256 + r0 + j] = s[j];
#pragma unroll
    for (int n = 0; n < 4; ++n)
#pragma unroll
      for (int k = 0; k < 2; ++k) {
        union { bf16 h[2]; uint32_t u; } pk;
        pk.h[0] = __float2bfloat16(acc[m][n][2 * k]);
        pk.h[1] = __float2bfloat16(acc[m][n][2 * k + 1]);
        lgtb[(size_t)(m * 8 + n * 2 + k) * 512] = pk.u;
      }
  }
  __syncthreads();
  if (tid < 256) {
    const float ssum = red[0 * 256 + tid] + red[1 * 256 + tid] +
                       red[2 * 256 + tid] + red[3 * 256 + tid];
    partials[(size_t)(bm * 256 + tid) * NPB + bn] =
        make_float2(red2[tid], ssum);
  }
}

// ---------------- lse reduce: 1024 rows x NPB partials -> lse[row] ---------
__global__ __launch_bounds__(128) void lse_reduce(
    const float2* __restrict__ partials, float* __restrict__ lse, int NPB) {
  const int row = blockIdx.x;
  const int t = threadIdx.x;
  float m = -3.4e38f, s = 0.0f;
  if (t < NPB) {
    float2 p = partials[(size_t)row * NPB + t];
    m = p.x;
    s = p.y;
  }
#pragma unroll
  for (int o = 32; o; o >>= 1) {
    const float om = __shfl_xor(m, o), os = __shfl_xor(s, o);
    const float nm = fmaxf(m, om);
    s = s * __expf(m - nm) + os * __expf(om - nm);
    m = nm;
  }
  __shared__ float sm[2], ss[2];
  if ((t & 63) == 0) { sm[t >> 6] = m; ss[t >> 6] = s; }
  __syncthreads();
  if (t == 0) {
    const float M = fmaxf(sm[0], sm[1]);
    const float S = ss[0] * __expf(sm[0] - M) + ss[1] * __expf(sm[1] - M);
    lse[row] = M + __logf(S);
  }
}

// --------- final: read fragment-layout bf16 logits, write log_softmax ------
__global__ __launch_bounds__(512) void ls_final(
    const uint32_t* __restrict__ lgt, const float* __restrict__ lse,
    float* __restrict__ out, int NPB) {
  const int blk = blockIdx.x;
  const int bm = blk / NPB, bn = blk % NPB;
  const int t = threadIdx.x;
  const int w = t >> 6, lane = t & 63;
  const int wr = w >> 2, wc = w & 3, q4 = lane >> 4, rAc = lane & 15;
  const uint32_t* src = lgt + (size_t)blk * (64 * 512) + t;
  const int col = bn * 256 + wc * 64 + rAc;
  const int row0 = bm * 256 + wr * 128 + q4 * 4;
#pragma unroll 4
  for (int fp = 0; fp < 64; ++fp) {
    const int m = fp >> 3, n = (fp >> 1) & 3, k = fp & 1;
    const uint32_t u = src[(size_t)fp * 512];
    const int r = row0 + m * 16 + 2 * k;
    const int c = col + n * 16;
    const float lo = __uint_as_float(u << 16);
    const float hi = __uint_as_float(u & 0xffff0000u);
    out[(size_t)r * 32000 + c] = lo - lse[r];
    out[(size_t)(r + 1) * 32000 + c] = hi - lse[r + 1];
  }
}

extern "C" void kernel_launch(void* const* d_in, const int* in_sizes, int n_in,
                              void* d_out, int out_size, void* d_ws,
                              size_t ws_size, hipStream_t stream) {
  const float* input  = (const float*)d_in[0];
  const float* hidden = (const float*)d_in[1];
  const float* W_i2g  = (const float*)d_in[2];
  const float* b_i2g  = (const float*)d_in[3];
  const float* W_x2h  = (const float*)d_in[4];
  const float* b_x2h  = (const float*)d_in[5];
  const float* W_h2h  = (const float*)d_in[6];
  const float* W_h2o  = (const float*)d_in[7];
  const float* b_h2o  = (const float*)d_in[8];

  float* out_ls = (float*)d_out;                 // [1024,32000]
  float* out_h  = out_ls + (size_t)1024 * 32000; // [1024,2048]

  char* ws = (char*)d_ws;
  bf16* inp_bf     = (bf16*)(ws + 0);          //  2 MB
  bf16* hid_bf     = (bf16*)(ws + 2097152);    //  4 MB
  bf16* wi_bf      = (bf16*)(ws + 6291456);    // 24 MB
  bf16* wx_bf      = (bf16*)(ws + 31457280);   //  4 MB
  bf16* wh_bf      = (bf16*)(ws + 35651584);   //  8 MB
  bf16* z_bf       = (bf16*)(ws + 44040192);   //  4 MB
  bf16* rh_bf      = (bf16*)(ws + 48234496);   //  4 MB
  bf16* h_bf       = (bf16*)(ws + 52428800);   //  4 MB
  bf16* wo_bf      = (bf16*)(ws + 56623104);   // 125 MB
  uint32_t* lgt    = (uint32_t*)(ws + 187695104);  // 65.5 MB
  float2* partials = (float2*)(ws + 253231104);    // 1 MB
  float* lse       = (float*)(ws + 254255104);     // 4 KB

  // g1 inputs only (wx/wh convert inside g1's launch; W_h2o inside g1+g2)
  CvtArgs ca;
  ca.src[0] = input;  ca.dst[0] = inp_bf; ca.n[0] = 1024 * 1024;
  ca.src[1] = hidden; ca.dst[1] = hid_bf; ca.n[1] = 1024 * 2048;
  ca.src[2] = W_i2g;  ca.dst[2] = wi_bf;  ca.n[2] = 4096 * 3072;
  const int bs[4] = {0, 34, 100, 512};
  for (int i = 0; i < 4; ++i) ca.bstart[i] = bs[i];
  cvt_all<<<512, 256, 0, stream>>>(ca);

  const int HALF_WO = 32000 * 2048 / 2;  // 32,768,000 elements

  // gates GEMM (256) + conv blocks (256): W_h2o half1 + W_x2h + W_h2h
  gemm128<1><<<256 + 256, 256, 0, stream>>>(
      inp_bf, hid_bf, 1024, 1024, 2048,
      wi_bf, wi_bf, 1 << 30, 3072, 3072,
      8, 4096, 3072, b_i2g, hidden, nullptr, z_bf, rh_bf, nullptr,
      256,
      W_h2o, wo_bf, HALF_WO,
      W_x2h, wx_bf, 2048 * 1024,
      W_h2h, wh_bf, 2048 * 2048);

  // h_cand GEMM (128) + conv blocks (384): W_h2o half2
  gemm128<2><<<128 + 384, 256, 0, stream>>>(
      inp_bf, rh_bf, 1024, 1024, 2048,
      wx_bf, wh_bf, 1024, 1024, 2048,
      8, 2048, 3072, b_x2h, hidden, z_bf, h_bf, nullptr, out_h,
      128,
      W_h2o + HALF_WO, wo_bf + HALF_WO, HALF_WO,
      nullptr, nullptr, 0,
      nullptr, nullptr, 0);

  // logits (bf16 frag layout) + per-block softmax partials
  gemm256_f<<<4 * 125, 512, 0, stream>>>(h_bf, wo_bf, b_h2o, lgt, partials,
                                         4, 2048, 125);

  // lse per row, then final log-softmax write
  lse_reduce<<<1024, 128, 0, stream>>>(partials, lse, 125);
  ls_final<<<500, 512, 0, stream>>>(lgt, lse, out_ls, 125);
}

// Round 17
// 364.156 us; speedup vs baseline: 1.0706x; 1.0143x over previous
//
#include <hip/hip_runtime.h>
#include <hip/hip_bf16.h>
#include <stdint.h>

using bf16 = __hip_bfloat16;
typedef __bf16 bf16x8 __attribute__((ext_vector_type(8)));
typedef float f32x4 __attribute__((ext_vector_type(4)));

__device__ __forceinline__ void gload_lds16(const bf16* g, bf16* l) {
  __builtin_amdgcn_global_load_lds(
      (const __attribute__((address_space(1))) void*)g,
      (__attribute__((address_space(3))) void*)l, 16, 0, 0);
}

#define BARRIER() asm volatile("s_barrier" ::: "memory")

// ---------------- merged f32 -> bf16 conversion (3 segments) ---------------
struct CvtArgs {
  const float* src[3];
  bf16* dst[3];
  int n[3];
  int bstart[4];
};

__global__ __launch_bounds__(256) void cvt_all(CvtArgs a) {
  int seg = 0;
#pragma unroll
  for (int i = 0; i < 2; ++i)
    if ((int)blockIdx.x >= a.bstart[i + 1]) seg = i + 1;
  const int nb = a.bstart[seg + 1] - a.bstart[seg];
  const int lb = blockIdx.x - a.bstart[seg];
  const float* __restrict__ in = a.src[seg];
  bf16* __restrict__ out = a.dst[seg];
  const int n = a.n[seg];
  const int stride = nb * 256 * 4;
  for (int i = (lb * 256 + (int)threadIdx.x) * 4; i < n; i += stride) {
    float4 v = *reinterpret_cast<const float4*>(in + i);
    union { bf16 h[4]; uint2 u; } o;
    o.h[0] = __float2bfloat16(v.x);
    o.h[1] = __float2bfloat16(v.y);
    o.h[2] = __float2bfloat16(v.z);
    o.h[3] = __float2bfloat16(v.w);
    *reinterpret_cast<uint2*>(out + i) = o.u;
  }
}

// --- 128x128 bf16 GEMM: BK=64, 2-phase prefetch, XOR-swizzled LDS ---------
// Converter blocks handle up to 3 (src,dst,n) segments via a virtual
// concatenated index (all n multiples of 4 -> float4 alignment holds).
template <int EPI>
__global__ __launch_bounds__(256)
void gemm128(const bf16* __restrict__ A0, const bf16* __restrict__ A1,
             int aSplit, int ldA0, int ldA1,
             const bf16* __restrict__ B0, const bf16* __restrict__ B1,
             int bSplit, int ldB0, int ldB1,
             int MB, int N, int K,
             const float* __restrict__ bias,
             const float* __restrict__ hidden,
             const bf16* __restrict__ zbuf,
             bf16* __restrict__ obf_a,
             bf16* __restrict__ obf_b,
             float* __restrict__ of32,
             int gemmBlocks,
             const float* __restrict__ csrc0, bf16* __restrict__ cdst0, int cn0,
             const float* __restrict__ csrc1, bf16* __restrict__ cdst1, int cn1,
             const float* __restrict__ csrc2, bf16* __restrict__ cdst2, int cn2) {
  const int tid = threadIdx.x;
  if ((int)blockIdx.x >= gemmBlocks) {  // ---- converter path ----
    const int cb = blockIdx.x - gemmBlocks;
    const int ncb = gridDim.x - gemmBlocks;
    const int stride = ncb * 256 * 4;
    const int tot = cn0 + cn1 + cn2;
    for (int i = (cb * 256 + tid) * 4; i < tot; i += stride) {
      const float* sp; bf16* dp; int off = i;
      if (off < cn0)            { sp = csrc0; dp = cdst0; }
      else if (off < cn0 + cn1) { sp = csrc1; dp = cdst1; off -= cn0; }
      else                      { sp = csrc2; dp = cdst2; off -= cn0 + cn1; }
      float4 v = *reinterpret_cast<const float4*>(sp + off);
      union { bf16 h[4]; uint2 u; } o;
      o.h[0] = __float2bfloat16(v.x);
      o.h[1] = __float2bfloat16(v.y);
      o.h[2] = __float2bfloat16(v.z);
      o.h[3] = __float2bfloat16(v.w);
      *reinterpret_cast<uint2*>(dp + off) = o.u;
    }
    return;
  }
  __shared__ bf16 lA[2][128 * 64];
  __shared__ bf16 lB[2][128 * 64];
  const int wave = tid >> 6;
  const int lane = tid & 63;
  const int cpx = gemmBlocks >> 3;
  const int swz = ((int)blockIdx.x & 7) * cpx + ((int)blockIdx.x >> 3);
  const int bm = swz % MB;
  const int bn = swz / MB;
  const int wr = wave >> 1, wc = wave & 1;   // 2x2 wave grid, 64x64 each
  const int l8 = lane >> 3;
  const int gcol = ((lane & 7) ^ l8) * 8;    // pre-swizzled global k offset
  const int lrow = lane & 15;
  const int kb0 = (lane >> 4) * 16;          // byte offset within 64B half
  const int xm = (lane & 7) << 4;            // read-side XOR = (row&7)*16
  const int nkt = K >> 6;

  auto STAGEK = [&](int buf, int kt) {
    if (kt >= nkt) return;
    const int kb = kt << 6;
    const bf16* Ap; int lda, ka;
    if (kb < aSplit) { Ap = A0; lda = ldA0; ka = kb; }
    else             { Ap = A1; lda = ldA1; ka = kb - aSplit; }
    const bf16* Bp; int ldb, kbb;
    if (kb < bSplit) { Bp = B0; ldb = ldB0; kbb = kb; }
    else             { Bp = B1; ldb = ldB1; kbb = kb - bSplit; }
#pragma unroll
    for (int h = 0; h < 2; ++h)
#pragma unroll
      for (int j = 0; j < 2; ++j) {
        const int r0 = h * 64 + wave * 16 + j * 8;
        gload_lds16(Ap + (size_t)(bm * 128 + r0 + l8) * lda + ka + gcol,
                    &lA[buf][r0 * 64]);
        gload_lds16(Bp + (size_t)(bn * 128 + r0 + l8) * ldb + kbb + gcol,
                    &lB[buf][r0 * 64]);
      }
  };
  auto RDA = [&](int buf, int row, int ks) {
    return *reinterpret_cast<const bf16x8*>(
        reinterpret_cast<const char*>(&lA[buf][0]) + row * 128 +
        ((ks * 64 + kb0) ^ xm));
  };
  auto RDB = [&](int buf, int row, int ks) {
    return *reinterpret_cast<const bf16x8*>(
        reinterpret_cast<const char*>(&lB[buf][0]) + row * 128 +
        ((ks * 64 + kb0) ^ xm));
  };

  f32x4 acc[4][4] = {};

  STAGEK(0, 0);
  asm volatile("s_waitcnt vmcnt(0)" ::: "memory");
  BARRIER();

  for (int kt = 0; kt < nkt; ++kt) {
    const int buf = kt & 1;
    STAGEK(buf ^ 1, kt + 1);  // prefetch next tile into the other buffer
    bf16x8 af[4][2], bfr[4][2];
#pragma unroll
    for (int f = 0; f < 4; ++f)
#pragma unroll
      for (int ks = 0; ks < 2; ++ks) {
        af[f][ks] = RDA(buf, wr * 64 + f * 16 + lrow, ks);
        bfr[f][ks] = RDB(buf, wc * 64 + f * 16 + lrow, ks);
      }
    __builtin_amdgcn_s_setprio(1);
#pragma unroll
    for (int fm = 0; fm < 4; ++fm)
#pragma unroll
      for (int fn = 0; fn < 4; ++fn)
#pragma unroll
        for (int ks = 0; ks < 2; ++ks)
          acc[fm][fn] = __builtin_amdgcn_mfma_f32_16x16x32_bf16(
              af[fm][ks], bfr[fn][ks], acc[fm][fn], 0, 0, 0);
    __builtin_amdgcn_s_setprio(0);
    asm volatile("s_waitcnt vmcnt(0)" ::: "memory");  // next tile landed
    BARRIER();  // all waves done reading buf + next tile complete
  }

  const int rb = bm * 128 + wr * 64 + (lane >> 4) * 4;
  const int cb = bn * 128 + wc * 64 + lrow;
#pragma unroll
  for (int fm = 0; fm < 4; ++fm) {
#pragma unroll
    for (int fn = 0; fn < 4; ++fn) {
#pragma unroll
      for (int j = 0; j < 4; ++j) {
        const int m = rb + fm * 16 + j;
        const int n = cb + fn * 16;
        float v = acc[fm][fn][j];
        if (EPI == 1) {
          v = 1.0f / (1.0f + __expf(-(v + bias[n])));
          if (n < 2048) {
            obf_a[(size_t)m * 2048 + n] = __float2bfloat16(v);
          } else {
            const int nn = n - 2048;
            obf_b[(size_t)m * 2048 + nn] =
                __float2bfloat16(v * hidden[(size_t)m * 2048 + nn]);
          }
        } else if (EPI == 2) {
          const float e = __expf(2.0f * (v + bias[n]));
          const float hc = (e - 1.0f) / (e + 1.0f);
          const float z = __bfloat162float(zbuf[(size_t)m * 2048 + n]);
          const float hd = hidden[(size_t)m * 2048 + n];
          const float h = z * hd + (1.0f - z) * hc;
          of32[(size_t)m * 2048 + n] = h;
          obf_a[(size_t)m * 2048 + n] = __float2bfloat16(h);
        }
      }
    }
  }
}

// ------ 256x256 8-phase bf16 GEMM, deep pipeline, front-loaded staging -----
// (K10 verified schedule: stages @ph0/1/4/5, vmcnt(8) after MFMA @ph3/ph7)
__global__ __launch_bounds__(512, 2)
void gemm256_f(const bf16* __restrict__ A, const bf16* __restrict__ W,
               const float* __restrict__ bias, uint32_t* __restrict__ lgt,
               float2* __restrict__ partials, int MB, int K, int NPB) {
  __shared__ bf16 lds[5][256 * 64];  // 163840 B = full LDS pool
  const int tid = threadIdx.x;
  const int w = tid >> 6, lane = tid & 63;
  const int nwg = gridDim.x;
  const int q8 = nwg >> 3, r8 = nwg & 7;
  const int xcd = (int)blockIdx.x & 7, lid = (int)blockIdx.x >> 3;
  const int swz =
      (xcd < r8 ? xcd * (q8 + 1) : r8 * (q8 + 1) + (xcd - r8) * q8) + lid;
  const int bm = swz % MB, bn = swz / MB;
  const int wr = w >> 2, wc = w & 3;   // 2x4 wave grid
  const int l8 = lane >> 3;
  const int gcol = ((lane & 7) ^ l8) * 8;   // pre-swizzled global k-elem ofs
  const int rA = lane & 15;
  const int kb0 = (lane >> 4) * 16;
  const int xm = (lane & 7) << 4;
  const int nkt = K >> 6, niter = nkt >> 1;
  const bf16* gA = A + (size_t)bm * 256 * K;
  const bf16* gB = W + (size_t)bn * 256 * K;

  auto STAGE2 = [&](int plane, int kt, const bf16* g) {  // full 256x64 tile
    if (kt > nkt - 1) kt = nkt - 1;  // clamp: keep vmcnt counts uniform
#pragma unroll
    for (int h = 0; h < 2; ++h) {
      const int r0 = h * 128 + w * 16;
#pragma unroll
      for (int j = 0; j < 2; ++j)
        gload_lds16(g + (size_t)(r0 + j * 8 + l8) * K + kt * 64 + gcol,
                    &lds[plane][(r0 + j * 8) * 64]);
    }
  };
  auto RD = [&](int plane, int row, int ks) {
    const int off = row * 128 + ((ks * 64 + kb0) ^ xm);
    return *reinterpret_cast<const bf16x8*>(
        reinterpret_cast<const char*>(&lds[plane][0]) + off);
  };

  f32x4 acc[8][4] = {};

  int a0 = 0, a1 = 1, a2 = 2;
  STAGE2(a0, 0, gA); STAGE2(3, 0, gB);
  STAGE2(a1, 1, gA); STAGE2(4, 1, gB);
  asm volatile("s_waitcnt vmcnt(8)" ::: "memory");
  BARRIER();

  for (int it = 0; it < niter; ++it) {
    const int t = it << 1;
    const bool last = (it == niter - 1);
    bf16x8 bfr[4][2];
#pragma unroll
    for (int ph = 0; ph < 8; ++ph) {
      const int buf = ph >> 2, q = ph & 3;
      const int ap = buf ? a1 : a0;
      const int bp = 3 + buf;
      bf16x8 af[2][2];
      if (q == 0) {
#pragma unroll
        for (int n = 0; n < 4; ++n)
#pragma unroll
          for (int ks = 0; ks < 2; ++ks)
            bfr[n][ks] = RD(bp, wc * 64 + n * 16 + rA, ks);
      }
#pragma unroll
      for (int mm = 0; mm < 2; ++mm)
#pragma unroll
        for (int ks = 0; ks < 2; ++ks)
          af[mm][ks] = RD(ap, wr * 128 + (q * 2 + mm) * 16 + rA, ks);

      if (ph == 0)      STAGE2(a2, t + 2, gA);  // a2 unused this iter
      else if (ph == 1) STAGE2(3, t + 2, gB);   // plane3 free after ph0 read
      else if (ph == 4) STAGE2(a0, t + 3, gA);  // a0 freed at ph3 barrier
      else if (ph == 5) STAGE2(4, t + 3, gB);   // plane4 free after ph4 read

      __builtin_amdgcn_s_setprio(1);
#pragma unroll
      for (int mm = 0; mm < 2; ++mm)
#pragma unroll
        for (int n = 0; n < 4; ++n)
#pragma unroll
          for (int ks = 0; ks < 2; ++ks)
            acc[q * 2 + mm][n] = __builtin_amdgcn_mfma_f32_16x16x32_bf16(
                af[mm][ks], bfr[n][ks], acc[q * 2 + mm][n], 0, 0, 0);
      __builtin_amdgcn_s_setprio(0);

      if (ph == 3 || ph == 7)
        asm volatile("s_waitcnt vmcnt(8)" ::: "memory");
      if (!(ph == 7 && last)) BARRIER();
    }
    // rotate A planes: next iter reads {A(t+2)=a2, A(t+3)=a0}; free = a1
    const int na0 = a2, na1 = a0, na2 = a1;
    a0 = na0; a1 = na1; a2 = na2;
  }
  asm volatile("s_waitcnt vmcnt(0) lgkmcnt(0)" ::: "memory");
  __syncthreads();  // all LDS traffic done; planes now reusable as scratch

  // ---- fused epilogue: bias, row stats, bf16 logits (fragment layout) ----
  float* red = (float*)&lds[0][0];     // [4][256] overlay
  float* red2 = red + 1024;            // [256]
  const int outc = bn * 256 + wc * 64 + rA;
  float bb[4];
#pragma unroll
  for (int n = 0; n < 4; ++n) bb[n] = bias[outc + n * 16];
#pragma unroll
  for (int m = 0; m < 8; ++m)
#pragma unroll
    for (int n = 0; n < 4; ++n)
#pragma unroll
      for (int j = 0; j < 4; ++j) acc[m][n][j] += bb[n];

  const int q4 = lane >> 4;
  const int rowb = wr * 128 + q4 * 4;
#pragma unroll
  for (int m = 0; m < 8; ++m)
#pragma unroll
    for (int j = 0; j < 4; ++j) {
      float x = fmaxf(fmaxf(acc[m][0][j], acc[m][1][j]),
                      fmaxf(acc[m][2][j], acc[m][3][j]));
      x = fmaxf(x, __shfl_xor(x, 1));
      x = fmaxf(x, __shfl_xor(x, 2));
      x = fmaxf(x, __shfl_xor(x, 4));
      x = fmaxf(x, __shfl_xor(x, 8));
      if (rA == 0) red[wc * 256 + rowb + m * 16 + j] = x;
    }
  __syncthreads();
  if (tid < 256)
    red2[tid] = fmaxf(fmaxf(red[0 * 256 + tid], red[1 * 256 + tid]),
                      fmaxf(red[2 * 256 + tid], red[3 * 256 + tid]));
  __syncthreads();

  uint32_t* lgtb = lgt + (size_t)(bm * NPB + bn) * (64 * 512) + tid;
#pragma unroll
  for (int m = 0; m < 8; ++m) {
    const int r0 = rowb + m * 16;
    float s[4];
#pragma unroll
    for (int j = 0; j < 4; ++j) {
      const float fm = red2[r0 + j];
      float e = __expf(acc[m][0][j] - fm) + __expf(acc[m][1][j] - fm) +
                __expf(acc[m][2][j] - fm) + __expf(acc[m][3][j] - fm);
      e += __shfl_xor(e, 1);
      e += __shfl_xor(e, 2);
      e += __shfl_xor(e, 4);
      e += __shfl_xor(e, 8);
      s[j] = e;
    }
#pragma unroll
    for (int j = 0; j < 4; ++j)
      if (rA == 0) red[wc * 256 + r0 + j] = s[j];
#pragma unroll
    for (int n = 0; n < 4; ++n)
#pragma unroll
      for (int k = 0; k < 2; ++k) {
        union { bf16 h[2]; uint32_t u; } pk;
        pk.h[0] = __float2bfloat16(acc[m][n][2 * k]);
        pk.h[1] = __float2bfloat16(acc[m][n][2 * k + 1]);
        lgtb[(size_t)(m * 8 + n * 2 + k) * 512] = pk.u;
      }
  }
  __syncthreads();
  if (tid < 256) {
    const float ssum = red[0 * 256 + tid] + red[1 * 256 + tid] +
                       red[2 * 256 + tid] + red[3 * 256 + tid];
    partials[(size_t)(bm * 256 + tid) * NPB + bn] =
        make_float2(red2[tid], ssum);
  }
}

// ---------------- lse reduce: 1024 rows x NPB partials -> lse[row] ---------
__global__ __launch_bounds__(128) void lse_reduce(
    const float2* __restrict__ partials, float* __restrict__ lse, int NPB) {
  const int row = blockIdx.x;
  const int t = threadIdx.x;
  float m = -3.4e38f, s = 0.0f;
  if (t < NPB) {
    float2 p = partials[(size_t)row * NPB + t];
    m = p.x;
    s = p.y;
  }
#pragma unroll
  for (int o = 32; o; o >>= 1) {
    const float om = __shfl_xor(m, o), os = __shfl_xor(s, o);
    const float nm = fmaxf(m, om);
    s = s * __expf(m - nm) + os * __expf(om - nm);
    m = nm;
  }
  __shared__ float sm[2], ss[2];
  if ((t & 63) == 0) { sm[t >> 6] = m; ss[t >> 6] = s; }
  __syncthreads();
  if (t == 0) {
    const float M = fmaxf(sm[0], sm[1]);
    const float S = ss[0] * __expf(sm[0] - M) + ss[1] * __expf(sm[1] - M);
    lse[row] = M + __logf(S);
  }
}

// --------- final: read fragment-layout bf16 logits, write log_softmax ------
__global__ __launch_bounds__(512) void ls_final(
    const uint32_t* __restrict__ lgt, const float* __restrict__ lse,
    float* __restrict__ out, int NPB) {
  const int blk = blockIdx.x;
  const int bm = blk / NPB, bn = blk % NPB;
  const int t = threadIdx.x;
  const int w = t >> 6, lane = t & 63;
  const int wr = w >> 2, wc = w & 3, q4 = lane >> 4, rAc = lane & 15;
  const uint32_t* src = lgt + (size_t)blk * (64 * 512) + t;
  const int col = bn * 256 + wc * 64 + rAc;
  const int row0 = bm * 256 + wr * 128 + q4 * 4;
#pragma unroll 4
  for (int fp = 0; fp < 64; ++fp) {
    const int m = fp >> 3, n = (fp >> 1) & 3, k = fp & 1;
    const uint32_t u = src[(size_t)fp * 512];
    const int r = row0 + m * 16 + 2 * k;
    const int c = col + n * 16;
    const float lo = __uint_as_float(u << 16);
    const float hi = __uint_as_float(u & 0xffff0000u);
    out[(size_t)r * 32000 + c] = lo - lse[r];
    out[(size_t)(r + 1) * 32000 + c] = hi - lse[r + 1];
  }
}

extern "C" void kernel_launch(void* const* d_in, const int* in_sizes, int n_in,
                              void* d_out, int out_size, void* d_ws,
                              size_t ws_size, hipStream_t stream) {
  const float* input  = (const float*)d_in[0];
  const float* hidden = (const float*)d_in[1];
  const float* W_i2g  = (const float*)d_in[2];
  const float* b_i2g  = (const float*)d_in[3];
  const float* W_x2h  = (const float*)d_in[4];
  const float* b_x2h  = (const float*)d_in[5];
  const float* W_h2h  = (const float*)d_in[6];
  const float* W_h2o  = (const float*)d_in[7];
  const float* b_h2o  = (const float*)d_in[8];

  float* out_ls = (float*)d_out;                 // [1024,32000]
  float* out_h  = out_ls + (size_t)1024 * 32000; // [1024,2048]

  char* ws = (char*)d_ws;
  bf16* inp_bf     = (bf16*)(ws + 0);          //  2 MB
  bf16* hid_bf     = (bf16*)(ws + 2097152);    //  4 MB
  bf16* wi_bf      = (bf16*)(ws + 6291456);    // 24 MB
  bf16* wx_bf      = (bf16*)(ws + 31457280);   //  4 MB
  bf16* wh_bf      = (bf16*)(ws + 35651584);   //  8 MB
  bf16* z_bf       = (bf16*)(ws + 44040192);   //  4 MB
  bf16* rh_bf      = (bf16*)(ws + 48234496);   //  4 MB
  bf16* h_bf       = (bf16*)(ws + 52428800);   //  4 MB
  bf16* wo_bf      = (bf16*)(ws + 56623104);   // 125 MB
  uint32_t* lgt    = (uint32_t*)(ws + 187695104);  // 65.5 MB
  float2* partials = (float2*)(ws + 253231104);    // 1 MB
  float* lse       = (float*)(ws + 254255104);     // 4 KB

  // g1 inputs only (wx/wh convert inside g1's launch; W_h2o inside g1+g2)
  CvtArgs ca;
  ca.src[0] = input;  ca.dst[0] = inp_bf; ca.n[0] = 1024 * 1024;
  ca.src[1] = hidden; ca.dst[1] = hid_bf; ca.n[1] = 1024 * 2048;
  ca.src[2] = W_i2g;  ca.dst[2] = wi_bf;  ca.n[2] = 4096 * 3072;
  const int bs[4] = {0, 34, 100, 512};
  for (int i = 0; i < 4; ++i) ca.bstart[i] = bs[i];
  cvt_all<<<512, 256, 0, stream>>>(ca);

  // W_h2o split 42/58 to equalize g1/g2 leg makespans (g1 also carries
  // wx+wh conversion and the larger GEMM). Both parts are x4-aligned.
  const int G1_WO = 27525120;
  const int G2_WO = 65536000 - G1_WO;  // 38,010,880

  // gates GEMM (256) + conv blocks (256): W_h2o part1 + W_x2h + W_h2h
  gemm128<1><<<256 + 256, 256, 0, stream>>>(
      inp_bf, hid_bf, 1024, 1024, 2048,
      wi_bf, wi_bf, 1 << 30, 3072, 3072,
      8, 4096, 3072, b_i2g, hidden, nullptr, z_bf, rh_bf, nullptr,
      256,
      W_h2o, wo_bf, G1_WO,
      W_x2h, wx_bf, 2048 * 1024,
      W_h2h, wh_bf, 2048 * 2048);

  // h_cand GEMM (128) + conv blocks (384): W_h2o part2
  gemm128<2><<<128 + 384, 256, 0, stream>>>(
      inp_bf, rh_bf, 1024, 1024, 2048,
      wx_bf, wh_bf, 1024, 1024, 2048,
      8, 2048, 3072, b_x2h, hidden, z_bf, h_bf, nullptr, out_h,
      128,
      W_h2o + G1_WO, wo_bf + G1_WO, G2_WO,
      nullptr, nullptr, 0,
      nullptr, nullptr, 0);

  // logits (bf16 frag layout) + per-block softmax partials
  gemm256_f<<<4 * 125, 512, 0, stream>>>(h_bf, wo_bf, b_h2o, lgt, partials,
                                         4, 2048, 125);

  // lse per row, then final log-softmax write
  lse_reduce<<<1024, 128, 0, stream>>>(partials, lse, 125);
  ls_final<<<500, 512, 0, stream>>>(lgt, lse, out_ls, 125);
}